// Round 9
// baseline (181.531 us; speedup 1.0000x reference)
//
#include <hip/hip_runtime.h>
#include <hip/hip_bf16.h>

typedef __attribute__((ext_vector_type(8))) short short8;
typedef __attribute__((ext_vector_type(4))) short short4v;
typedef __attribute__((ext_vector_type(4))) float float4v;

#define S_DIM 128
#define N_DIM 256
#define CM    256
#define CH    32
#define CZ    128

static __device__ __forceinline__ short f2bf(float v) {
    return __builtin_bit_cast(short, __float2bfloat16(v));
}

// ---------------------------------------------------------------------------
// a_f/b_f global layout = MFMA fragment order:
//   element (row, k)  [row = n*32+c (a) or n*32+d (b), k = s]
//   -> a_f[(x*4 + sk)*512 + q*128 + (row&15)*8 + (k&7)]
//      x = row>>4, sk = k>>5, q = (k>>3)&3   (lane l = q*16 + (row&15))
// Every main-kernel load of these arrays is base + l*8 (lane-linear 1KB).
// ---------------------------------------------------------------------------

// ---------------------------------------------------------------------------
// Fused aux kernel, 640 blocks x 256 thr (unchanged from R8):
//   blocks [0,512):   LN + dual projection. Block = 2 n x 32 s x 64 cols.
//   blocks [512,576): wo -> fragment-ordered wo_f.
//   blocks [576,640): ninv[i][j] = 1/(sum_s mask[s,i]mask[s,j] + 1e-3).
// ---------------------------------------------------------------------------
__global__ __launch_bounds__(256) void prep_aux_kernel(
    const float* __restrict__ m, const float* __restrict__ mask,
    const float* __restrict__ lnw, const float* __restrict__ lnb,
    const float* __restrict__ w1, const float* __restrict__ b1,
    const float* __restrict__ w2, const float* __restrict__ b2,
    const float* __restrict__ wo, const float* __restrict__ bo,
    __hip_bfloat16* __restrict__ a_f, __hip_bfloat16* __restrict__ b_f,
    __hip_bfloat16* __restrict__ wo_f, float* __restrict__ ninv)
{
    __shared__ __align__(16) char lds_raw[77824];
    __hip_bfloat16* ln_lds = (__hip_bfloat16*)lds_raw;             // 64 x 264
    __hip_bfloat16* w_lds  = (__hip_bfloat16*)(lds_raw + 33792);   // 64 x 264
    __hip_bfloat16* st_lds = (__hip_bfloat16*)(lds_raw + 67584);   // 128 x 40

    const int bid = blockIdx.x, t = threadIdx.x;

    if (bid >= 576) {                       // ---- norm ----
        int i0 = (bid - 576) * 4, j = t;
        float a0 = 0.f, a1 = 0.f, a2 = 0.f, a3 = 0.f;
        for (int s = 0; s < S_DIM; ++s) {
            float mj = mask[s * N_DIM + j];
            a0 += mask[s * N_DIM + i0 + 0] * mj;
            a1 += mask[s * N_DIM + i0 + 1] * mj;
            a2 += mask[s * N_DIM + i0 + 2] * mj;
            a3 += mask[s * N_DIM + i0 + 3] * mj;
        }
        ninv[(i0 + 0) * N_DIM + j] = 1.0f / (a0 + 1e-3f);
        ninv[(i0 + 1) * N_DIM + j] = 1.0f / (a1 + 1e-3f);
        ninv[(i0 + 2) * N_DIM + j] = 1.0f / (a2 + 1e-3f);
        ninv[(i0 + 3) * N_DIM + j] = 1.0f / (a3 + 1e-3f);
        return;
    }
    if (bid >= 512) {                       // ---- wot ----
        int fidx = (bid - 512) * 256 + t;   // 16384 lane-slots
        int l  = fidx & 63;
        int d  = (fidx >> 6) & 31;
        int zt = fidx >> 11;
        int z  = zt * 16 + (l & 15);
        int cb = (l >> 4) * 8;
        short8 frag;
        #pragma unroll
        for (int j = 0; j < 8; ++j)
            frag[j] = f2bf(wo[(size_t)((cb + j) * 32 + d) * CZ + z]);
        *(short8*)&wo_f[(size_t)fidx * 8] = frag;
        return;
    }

    // ---- prep: 2 n x 32 s per block ----
    const int lane = t & 63, wv = t >> 6;
    const int q = lane >> 4, c16 = lane & 15;
    const int n0 = (bid & 127) * 2, s0 = (bid >> 7) * 32, sk = bid >> 7;

    #pragma unroll 4
    for (int i = 0; i < 64; ++i) {
        int e = i * 256 + t;
        int k = e >> 6, c = e & 63;
        float v = (c < CH) ? w1[k * CH + c] : w2[k * CH + (c - CH)];
        w_lds[c * 264 + k] = __float2bfloat16(v);
    }

    float4 lw = ((const float4*)lnw)[lane];
    float4 lb = ((const float4*)lnb)[lane];

    #pragma unroll 2
    for (int it = 0; it < 16; ++it) {
        int rl = wv * 16 + it;
        int r  = (s0 + (rl >> 1)) * N_DIM + n0 + (rl & 1);
        float4 mv = ((const float4*)(m + (size_t)r * CM))[lane];
        float s1 = mv.x + mv.y + mv.z + mv.w;
        float s2 = mv.x*mv.x + mv.y*mv.y + mv.z*mv.z + mv.w*mv.w;
        #pragma unroll
        for (int o = 32; o > 0; o >>= 1) {
            s1 += __shfl_xor(s1, o, 64);
            s2 += __shfl_xor(s2, o, 64);
        }
        float mu  = s1 * (1.0f / 256.0f);
        float var = s2 * (1.0f / 256.0f) - mu * mu;
        float rs  = rsqrtf(var + 1e-5f);
        int base = rl * 264 + lane * 4;
        ln_lds[base + 0] = __float2bfloat16((mv.x - mu) * rs * lw.x + lb.x);
        ln_lds[base + 1] = __float2bfloat16((mv.y - mu) * rs * lw.y + lb.y);
        ln_lds[base + 2] = __float2bfloat16((mv.z - mu) * rs * lw.z + lb.z);
        ln_lds[base + 3] = __float2bfloat16((mv.w - mu) * rs * lw.w + lb.w);
    }
    __syncthreads();

    float4v acc[4];
    #pragma unroll
    for (int ct = 0; ct < 4; ++ct) acc[ct] = (float4v){0.f, 0.f, 0.f, 0.f};
    #pragma unroll
    for (int ks = 0; ks < 8; ++ks) {
        int k0 = ks * 32 + q * 8;
        short8 af = *(const short8*)&ln_lds[(wv * 16 + c16) * 264 + k0];
        #pragma unroll
        for (int ct = 0; ct < 4; ++ct) {
            short8 wb = *(const short8*)&w_lds[(ct * 16 + c16) * 264 + k0];
            acc[ct] = __builtin_amdgcn_mfma_f32_16x16x32_bf16(af, wb, acc[ct], 0, 0, 0);
        }
    }

    #pragma unroll
    for (int ct = 0; ct < 4; ++ct) {
        int cc = ct * 16 + c16;
        float bias = (cc < CH) ? b1[cc] : b2[cc - CH];
        #pragma unroll
        for (int rr = 0; rr < 4; ++rr) {
            int rl = wv * 16 + q * 4 + rr;
            int r  = (s0 + (rl >> 1)) * N_DIM + n0 + (rl & 1);
            float val = (acc[ct][rr] + bias) * mask[r];
            st_lds[((rl & 1) * 64 + cc) * 40 + (rl >> 1)] = __float2bfloat16(val);
        }
    }
    __syncthreads();

    #pragma unroll
    for (int i = 0; i < 2; ++i) {
        int slot = i * 256 + t;
        int f8 = slot >> 6, l = slot & 63;
        int fl = f8 & 3, nl = fl >> 1, cch = fl & 1;
        int lq = l >> 4, lc16 = l & 15;
        int col = nl * 64 + (f8 >= 4 ? 32 : 0) + cch * 16 + lc16;
        short8 v = *(const short8*)&st_lds[col * 40 + lq * 8];
        __hip_bfloat16* base = (f8 >= 4) ? b_f : a_f;
        *(short8*)&base[(size_t)((n0 * 2 + fl) * 4 + sk) * 512 + l * 8] = v;
    }
}

// ---------------------------------------------------------------------------
// Main kernel v6: 512 thr (8 waves), 128 I x 256 J per block, PER-TAU
// epilogue. LDS = single region [0,16640) shorts (32.5 KB): B full-K stage
// (32 frags x 512) overlaid by P (32 frags x 520). 3 blocks/CU (24 waves).
// wo_f read once per tau (2x per block) -- trades L2 BW for occupancy.
// ---------------------------------------------------------------------------
__global__ __launch_bounds__(512, 6) void main_kernel(
    const __hip_bfloat16* __restrict__ a_f, const __hip_bfloat16* __restrict__ b_f,
    const __hip_bfloat16* __restrict__ wo_f, const float* __restrict__ bo,
    const float* __restrict__ ninv, float* __restrict__ out)
{
    __shared__ __align__(16) short lds[16640];

    const int t = threadIdx.x, l = t & 63, wv = t >> 6;   // wv 0..7
    const int q = l >> 4, c16 = l & 15;
    const int bi = blockIdx.x, bj0 = blockIdx.y * 2;
    const int wr = wv & 3, wc = wv >> 2;
    const size_t Ix = (size_t)bi * 8;
    const __hip_bfloat16* wbase = wo_f + (size_t)wv * 32 * 512;
    const int gi = bi * 4 + q;
    const int z  = wv * 16 + c16;
    const float bz = bo[z];

    #pragma unroll
    for (int tau = 0; tau < 2; ++tau) {
        const size_t Jx = (size_t)(bj0 + tau) * 8;

        // stage B (full K): frag f = xl*4 + sk, 4 frags per wave
        #pragma unroll
        for (int i = 0; i < 4; ++i) {
            int f  = i * 8 + wv;
            int xl = f >> 2, sk = f & 3;
            *(short8*)&lds[f * 512 + l * 8] =
                *(const short8*)&b_f[((Jx + xl) * 4 + sk) * 512 + l * 8];
        }
        // A fragments (L2-hot after tau 0; lane-linear)
        short8 af[4][2];
        #pragma unroll
        for (int sk = 0; sk < 4; ++sk)
            #pragma unroll
            for (int ti = 0; ti < 2; ++ti)
                af[sk][ti] = *(const short8*)&a_f[((Ix + wr * 2 + ti) * 4 + sk) * 512 + l * 8];
        __syncthreads();

        float4v acc[2][4];
        #pragma unroll
        for (int ti = 0; ti < 2; ++ti)
            #pragma unroll
            for (int tj = 0; tj < 4; ++tj)
                acc[ti][tj] = (float4v){0.f, 0.f, 0.f, 0.f};

        #pragma unroll
        for (int sk = 0; sk < 4; ++sk) {
            short8 bf[4];
            #pragma unroll
            for (int tj = 0; tj < 4; ++tj)
                bf[tj] = *(const short8*)&lds[((wc * 4 + tj) * 4 + sk) * 512 + l * 8];
            #pragma unroll
            for (int ti = 0; ti < 2; ++ti)
                #pragma unroll
                for (int tj = 0; tj < 4; ++tj)
                    acc[ti][tj] = __builtin_amdgcn_mfma_f32_16x16x32_bf16(
                        af[sk][ti], bf[tj], acc[ti][tj], 0, 0, 0);
        }
        __syncthreads();   // all B reads done; region becomes P

        // scatter acc -> P (overlaying B). (pair p, c=Il&31, d=Jl&31) ->
        // frag d, offset (c>>3)*128 + p*8 + (c&7), stride 520.
        #pragma unroll
        for (int ti = 0; ti < 2; ++ti)
            #pragma unroll
            for (int tj = 0; tj < 4; ++tj) {
                int d  = ((tj & 1) * 16) + c16;
                int c0 = ti * 16 + q * 4;
                int p  = wr * 4 + wc * 2 + (tj >> 1);
                short4v pk;
                #pragma unroll
                for (int rr = 0; rr < 4; ++rr)
                    pk[rr] = f2bf(acc[ti][tj][rr]);
                *(short4v*)&lds[d * 520 + (c0 >> 3) * 128 + p * 8 + (c0 & 7)] = pk;
            }
        __syncthreads();   // P ready

        // epilogue for this tau: wave wv owns z-tile wv
        float4v oacc = {0.f, 0.f, 0.f, 0.f};
        #pragma unroll 4
        for (int d = 0; d < 32; ++d) {
            short8 pf = *(const short8*)&lds[d * 520 + l * 8];
            short8 wf = *(const short8*)&wbase[(size_t)(d * 512 + l * 8)];
            oacc = __builtin_amdgcn_mfma_f32_16x16x32_bf16(pf, wf, oacc, 0, 0, 0);
        }

        const int bj = bj0 + tau;
        #pragma unroll
        for (int rr = 0; rr < 4; ++rr) {
            int gj = bj * 4 + rr;
            float nv = ninv[gi * N_DIM + gj];
            out[((size_t)gi * N_DIM + gj) * CZ + z] = (oacc[rr] + bz) * nv;
        }

        if (tau == 0) __syncthreads();   // P reads done before B restage
    }
}

extern "C" void kernel_launch(void* const* d_in, const int* in_sizes, int n_in,
                              void* d_out, int out_size, void* d_ws, size_t ws_size,
                              hipStream_t stream) {
    const float* m    = (const float*)d_in[0];
    const float* mask = (const float*)d_in[1];
    const float* lnw  = (const float*)d_in[2];
    const float* lnb  = (const float*)d_in[3];
    const float* w1   = (const float*)d_in[4];
    const float* b1   = (const float*)d_in[5];
    const float* w2   = (const float*)d_in[6];
    const float* b2   = (const float*)d_in[7];
    const float* wo   = (const float*)d_in[8];
    const float* bo   = (const float*)d_in[9];
    float* out = (float*)d_out;

    char* ws = (char*)d_ws;
    __hip_bfloat16* a_f  = (__hip_bfloat16*)ws;                          // 2 MB
    __hip_bfloat16* b_f  = (__hip_bfloat16*)(ws + (2u << 20));           // 2 MB
    __hip_bfloat16* wo_f = (__hip_bfloat16*)(ws + (4u << 20));           // 256 KB
    float*          ninv = (float*)(ws + (4u << 20) + (256u << 10));     // 256 KB

    prep_aux_kernel<<<640, 256, 0, stream>>>(m, mask, lnw, lnb, w1, b1, w2, b2,
                                             wo, bo, a_f, b_f, wo_f, ninv);
    main_kernel<<<dim3(64, 32), 512, 0, stream>>>(a_f, b_f, wo_f, bo, ninv, out);
}

// Round 10
// 159.299 us; speedup vs baseline: 1.1396x; 1.1396x over previous
//
#include <hip/hip_runtime.h>
#include <hip/hip_bf16.h>

typedef __attribute__((ext_vector_type(8))) short short8;
typedef __attribute__((ext_vector_type(4))) short short4v;
typedef __attribute__((ext_vector_type(4))) float float4v;

#define S_DIM 128
#define N_DIM 256
#define CM    256
#define CH    32
#define CZ    128

#define AS1 __attribute__((address_space(1)))
#define AS3 __attribute__((address_space(3)))

static __device__ __forceinline__ short f2bf(float v) {
    return __builtin_bit_cast(short, __float2bfloat16(v));
}

// ---------------------------------------------------------------------------
// a_f/b_f global layout = MFMA fragment order:
//   element (row, k)  [row = n*32+c (a) or n*32+d (b), k = s]
//   -> a_f[(x*4 + sk)*512 + q*128 + (row&15)*8 + (k&7)]
//      x = row>>4, sk = k>>5, q = (k>>3)&3   (lane l = q*16 + (row&15))
// Every main-kernel load of these arrays is base + l*8 (lane-linear 1KB).
// ---------------------------------------------------------------------------

// ---------------------------------------------------------------------------
// Fused aux kernel, 640 blocks x 256 thr (unchanged from R8):
//   blocks [0,512):   LN + dual projection. Block = 2 n x 32 s x 64 cols.
//   blocks [512,576): wo -> fragment-ordered wo_f.
//   blocks [576,640): ninv[i][j] = 1/(sum_s mask[s,i]mask[s,j] + 1e-3).
// ---------------------------------------------------------------------------
__global__ __launch_bounds__(256) void prep_aux_kernel(
    const float* __restrict__ m, const float* __restrict__ mask,
    const float* __restrict__ lnw, const float* __restrict__ lnb,
    const float* __restrict__ w1, const float* __restrict__ b1,
    const float* __restrict__ w2, const float* __restrict__ b2,
    const float* __restrict__ wo, const float* __restrict__ bo,
    __hip_bfloat16* __restrict__ a_f, __hip_bfloat16* __restrict__ b_f,
    __hip_bfloat16* __restrict__ wo_f, float* __restrict__ ninv)
{
    __shared__ __align__(16) char lds_raw[77824];
    __hip_bfloat16* ln_lds = (__hip_bfloat16*)lds_raw;             // 64 x 264
    __hip_bfloat16* w_lds  = (__hip_bfloat16*)(lds_raw + 33792);   // 64 x 264
    __hip_bfloat16* st_lds = (__hip_bfloat16*)(lds_raw + 67584);   // 128 x 40

    const int bid = blockIdx.x, t = threadIdx.x;

    if (bid >= 576) {                       // ---- norm ----
        int i0 = (bid - 576) * 4, j = t;
        float a0 = 0.f, a1 = 0.f, a2 = 0.f, a3 = 0.f;
        for (int s = 0; s < S_DIM; ++s) {
            float mj = mask[s * N_DIM + j];
            a0 += mask[s * N_DIM + i0 + 0] * mj;
            a1 += mask[s * N_DIM + i0 + 1] * mj;
            a2 += mask[s * N_DIM + i0 + 2] * mj;
            a3 += mask[s * N_DIM + i0 + 3] * mj;
        }
        ninv[(i0 + 0) * N_DIM + j] = 1.0f / (a0 + 1e-3f);
        ninv[(i0 + 1) * N_DIM + j] = 1.0f / (a1 + 1e-3f);
        ninv[(i0 + 2) * N_DIM + j] = 1.0f / (a2 + 1e-3f);
        ninv[(i0 + 3) * N_DIM + j] = 1.0f / (a3 + 1e-3f);
        return;
    }
    if (bid >= 512) {                       // ---- wot ----
        int fidx = (bid - 512) * 256 + t;   // 16384 lane-slots
        int l  = fidx & 63;
        int d  = (fidx >> 6) & 31;
        int zt = fidx >> 11;
        int z  = zt * 16 + (l & 15);
        int cb = (l >> 4) * 8;
        short8 frag;
        #pragma unroll
        for (int j = 0; j < 8; ++j)
            frag[j] = f2bf(wo[(size_t)((cb + j) * 32 + d) * CZ + z]);
        *(short8*)&wo_f[(size_t)fidx * 8] = frag;
        return;
    }

    // ---- prep: 2 n x 32 s per block ----
    const int lane = t & 63, wv = t >> 6;
    const int q = lane >> 4, c16 = lane & 15;
    const int n0 = (bid & 127) * 2, s0 = (bid >> 7) * 32, sk = bid >> 7;

    #pragma unroll 4
    for (int i = 0; i < 64; ++i) {
        int e = i * 256 + t;
        int k = e >> 6, c = e & 63;
        float v = (c < CH) ? w1[k * CH + c] : w2[k * CH + (c - CH)];
        w_lds[c * 264 + k] = __float2bfloat16(v);
    }

    float4 lw = ((const float4*)lnw)[lane];
    float4 lb = ((const float4*)lnb)[lane];

    #pragma unroll 2
    for (int it = 0; it < 16; ++it) {
        int rl = wv * 16 + it;
        int r  = (s0 + (rl >> 1)) * N_DIM + n0 + (rl & 1);
        float4 mv = ((const float4*)(m + (size_t)r * CM))[lane];
        float s1 = mv.x + mv.y + mv.z + mv.w;
        float s2 = mv.x*mv.x + mv.y*mv.y + mv.z*mv.z + mv.w*mv.w;
        #pragma unroll
        for (int o = 32; o > 0; o >>= 1) {
            s1 += __shfl_xor(s1, o, 64);
            s2 += __shfl_xor(s2, o, 64);
        }
        float mu  = s1 * (1.0f / 256.0f);
        float var = s2 * (1.0f / 256.0f) - mu * mu;
        float rs  = rsqrtf(var + 1e-5f);
        int base = rl * 264 + lane * 4;
        ln_lds[base + 0] = __float2bfloat16((mv.x - mu) * rs * lw.x + lb.x);
        ln_lds[base + 1] = __float2bfloat16((mv.y - mu) * rs * lw.y + lb.y);
        ln_lds[base + 2] = __float2bfloat16((mv.z - mu) * rs * lw.z + lb.z);
        ln_lds[base + 3] = __float2bfloat16((mv.w - mu) * rs * lw.w + lb.w);
    }
    __syncthreads();

    float4v acc[4];
    #pragma unroll
    for (int ct = 0; ct < 4; ++ct) acc[ct] = (float4v){0.f, 0.f, 0.f, 0.f};
    #pragma unroll
    for (int ks = 0; ks < 8; ++ks) {
        int k0 = ks * 32 + q * 8;
        short8 af = *(const short8*)&ln_lds[(wv * 16 + c16) * 264 + k0];
        #pragma unroll
        for (int ct = 0; ct < 4; ++ct) {
            short8 wb = *(const short8*)&w_lds[(ct * 16 + c16) * 264 + k0];
            acc[ct] = __builtin_amdgcn_mfma_f32_16x16x32_bf16(af, wb, acc[ct], 0, 0, 0);
        }
    }

    #pragma unroll
    for (int ct = 0; ct < 4; ++ct) {
        int cc = ct * 16 + c16;
        float bias = (cc < CH) ? b1[cc] : b2[cc - CH];
        #pragma unroll
        for (int rr = 0; rr < 4; ++rr) {
            int rl = wv * 16 + q * 4 + rr;
            int r  = (s0 + (rl >> 1)) * N_DIM + n0 + (rl & 1);
            float val = (acc[ct][rr] + bias) * mask[r];
            st_lds[((rl & 1) * 64 + cc) * 40 + (rl >> 1)] = __float2bfloat16(val);
        }
    }
    __syncthreads();

    #pragma unroll
    for (int i = 0; i < 2; ++i) {
        int slot = i * 256 + t;
        int f8 = slot >> 6, l = slot & 63;
        int fl = f8 & 3, nl = fl >> 1, cch = fl & 1;
        int lq = l >> 4, lc16 = l & 15;
        int col = nl * 64 + (f8 >= 4 ? 32 : 0) + cch * 16 + lc16;
        short8 v = *(const short8*)&st_lds[col * 40 + lq * 8];
        __hip_bfloat16* base = (f8 >= 4) ? b_f : a_f;
        *(short8*)&base[(size_t)((n0 * 2 + fl) * 4 + sk) * 512 + l * 8] = v;
    }
}

// ---------------------------------------------------------------------------
// Main kernel v7: 512 thr (8 waves), 128 I x 256 J per block, per-tau
// epilogue, LDS 32.5 KB -> 3 blocks/CU. Register-diet vs v6:
//   - af loaded per-sk inside NON-UNROLLED K loop (8 VGPR, not 32)
//   - B staged via global_load_lds width=16 (0 VGPR round-trip)
// Live set ~70 VGPR -> fits the 84-cap of __launch_bounds__(512,6), no spill.
// ---------------------------------------------------------------------------
__global__ __launch_bounds__(512, 6) void main_kernel(
    const __hip_bfloat16* __restrict__ a_f, const __hip_bfloat16* __restrict__ b_f,
    const __hip_bfloat16* __restrict__ wo_f, const float* __restrict__ bo,
    const float* __restrict__ ninv, float* __restrict__ out)
{
    __shared__ __align__(16) short lds[16640];

    const int t = threadIdx.x, l = t & 63, wv = t >> 6;   // wv 0..7
    const int q = l >> 4, c16 = l & 15;
    const int bi = blockIdx.x, bj0 = blockIdx.y * 2;
    const int wr = wv & 3, wc = wv >> 2;
    const size_t Ix = (size_t)bi * 8;
    const __hip_bfloat16* wbase = wo_f + (size_t)wv * 32 * 512;
    const int gi = bi * 4 + q;
    const int z  = wv * 16 + c16;
    const float bz = bo[z];

    #pragma unroll
    for (int tau = 0; tau < 2; ++tau) {
        const size_t Jx = (size_t)(bj0 + tau) * 8;

        // stage B (full K) via direct-to-LDS DMA: frag f = xl*4 + sk
        #pragma unroll
        for (int i = 0; i < 4; ++i) {
            int f = i * 8 + wv;
            __builtin_amdgcn_global_load_lds(
                (AS1 const void*)&b_f[((Jx + (f >> 2)) * 4 + (f & 3)) * 512 + l * 8],
                (AS3 void*)&lds[f * 512], 16, 0, 0);
        }
        __syncthreads();   // drains vmcnt; B visible

        float4v acc[2][4];
        #pragma unroll
        for (int ti = 0; ti < 2; ++ti)
            #pragma unroll
            for (int tj = 0; tj < 4; ++tj)
                acc[ti][tj] = (float4v){0.f, 0.f, 0.f, 0.f};

        #pragma unroll 1          // keep af loads in-loop (register diet)
        for (int sk = 0; sk < 4; ++sk) {
            short8 af0 = *(const short8*)&a_f[((Ix + wr * 2 + 0) * 4 + sk) * 512 + l * 8];
            short8 af1 = *(const short8*)&a_f[((Ix + wr * 2 + 1) * 4 + sk) * 512 + l * 8];
            short8 bf[4];
            #pragma unroll
            for (int tj = 0; tj < 4; ++tj)
                bf[tj] = *(const short8*)&lds[((wc * 4 + tj) * 4 + sk) * 512 + l * 8];
            #pragma unroll
            for (int tj = 0; tj < 4; ++tj) {
                acc[0][tj] = __builtin_amdgcn_mfma_f32_16x16x32_bf16(af0, bf[tj], acc[0][tj], 0, 0, 0);
                acc[1][tj] = __builtin_amdgcn_mfma_f32_16x16x32_bf16(af1, bf[tj], acc[1][tj], 0, 0, 0);
            }
        }
        __syncthreads();   // all B reads done; region becomes P

        // scatter acc -> P (overlaying B). (pair p, c=Il&31, d=Jl&31) ->
        // frag d, offset (c>>3)*128 + p*8 + (c&7), stride 520.
        #pragma unroll
        for (int ti = 0; ti < 2; ++ti)
            #pragma unroll
            for (int tj = 0; tj < 4; ++tj) {
                int d  = ((tj & 1) * 16) + c16;
                int c0 = ti * 16 + q * 4;
                int p  = wr * 4 + wc * 2 + (tj >> 1);
                short4v pk;
                #pragma unroll
                for (int rr = 0; rr < 4; ++rr)
                    pk[rr] = f2bf(acc[ti][tj][rr]);
                *(short4v*)&lds[d * 520 + (c0 >> 3) * 128 + p * 8 + (c0 & 7)] = pk;
            }
        __syncthreads();   // P ready

        // epilogue for this tau: wave wv owns z-tile wv
        float4v oacc = {0.f, 0.f, 0.f, 0.f};
        #pragma unroll 4
        for (int d = 0; d < 32; ++d) {
            short8 pf = *(const short8*)&lds[d * 520 + l * 8];
            short8 wf = *(const short8*)&wbase[(size_t)(d * 512 + l * 8)];
            oacc = __builtin_amdgcn_mfma_f32_16x16x32_bf16(pf, wf, oacc, 0, 0, 0);
        }

        const int bj = bj0 + tau;
        #pragma unroll
        for (int rr = 0; rr < 4; ++rr) {
            int gj = bj * 4 + rr;
            float nv = ninv[gi * N_DIM + gj];
            out[((size_t)gi * N_DIM + gj) * CZ + z] = (oacc[rr] + bz) * nv;
        }

        if (tau == 0) __syncthreads();   // P reads done before B restage
    }
}

extern "C" void kernel_launch(void* const* d_in, const int* in_sizes, int n_in,
                              void* d_out, int out_size, void* d_ws, size_t ws_size,
                              hipStream_t stream) {
    const float* m    = (const float*)d_in[0];
    const float* mask = (const float*)d_in[1];
    const float* lnw  = (const float*)d_in[2];
    const float* lnb  = (const float*)d_in[3];
    const float* w1   = (const float*)d_in[4];
    const float* b1   = (const float*)d_in[5];
    const float* w2   = (const float*)d_in[6];
    const float* b2   = (const float*)d_in[7];
    const float* wo   = (const float*)d_in[8];
    const float* bo   = (const float*)d_in[9];
    float* out = (float*)d_out;

    char* ws = (char*)d_ws;
    __hip_bfloat16* a_f  = (__hip_bfloat16*)ws;                          // 2 MB
    __hip_bfloat16* b_f  = (__hip_bfloat16*)(ws + (2u << 20));           // 2 MB
    __hip_bfloat16* wo_f = (__hip_bfloat16*)(ws + (4u << 20));           // 256 KB
    float*          ninv = (float*)(ws + (4u << 20) + (256u << 10));     // 256 KB

    prep_aux_kernel<<<640, 256, 0, stream>>>(m, mask, lnw, lnb, w1, b1, w2, b2,
                                             wo, bo, a_f, b_f, wo_f, ninv);
    main_kernel<<<dim3(64, 32), 512, 0, stream>>>(a_f, b_f, wo_f, bo, ninv, out);
}

// Round 11
// 146.860 us; speedup vs baseline: 1.2361x; 1.0847x over previous
//
#include <hip/hip_runtime.h>
#include <hip/hip_bf16.h>

typedef __attribute__((ext_vector_type(8))) short short8;
typedef __attribute__((ext_vector_type(4))) short short4v;
typedef __attribute__((ext_vector_type(4))) float float4v;

#define S_DIM 128
#define N_DIM 256
#define CM    256
#define CH    32
#define CZ    128

#define AS1 __attribute__((address_space(1)))
#define AS3 __attribute__((address_space(3)))

static __device__ __forceinline__ short f2bf(float v) {
    return __builtin_bit_cast(short, __float2bfloat16(v));
}

// ---------------------------------------------------------------------------
// a_f/b_f global layout = MFMA fragment order:
//   element (row, k)  [row = n*32+c (a) or n*32+d (b), k = s]
//   -> a_f[(x*4 + sk)*512 + q*128 + (row&15)*8 + (k&7)]
//      x = row>>4, sk = k>>5, q = (k>>3)&3   (lane l = q*16 + (row&15))
// Every main-kernel load of these arrays is base + l*8 (lane-linear 1KB).
// ---------------------------------------------------------------------------

// ---------------------------------------------------------------------------
// Fused aux kernel, 640 blocks x 256 thr (unchanged from R8):
//   blocks [0,512):   LN + dual projection. Block = 2 n x 32 s x 64 cols.
//   blocks [512,576): wo -> fragment-ordered wo_f.
//   blocks [576,640): ninv[i][j] = 1/(sum_s mask[s,i]mask[s,j] + 1e-3).
// ---------------------------------------------------------------------------
__global__ __launch_bounds__(256) void prep_aux_kernel(
    const float* __restrict__ m, const float* __restrict__ mask,
    const float* __restrict__ lnw, const float* __restrict__ lnb,
    const float* __restrict__ w1, const float* __restrict__ b1,
    const float* __restrict__ w2, const float* __restrict__ b2,
    const float* __restrict__ wo, const float* __restrict__ bo,
    __hip_bfloat16* __restrict__ a_f, __hip_bfloat16* __restrict__ b_f,
    __hip_bfloat16* __restrict__ wo_f, float* __restrict__ ninv)
{
    __shared__ __align__(16) char lds_raw[77824];
    __hip_bfloat16* ln_lds = (__hip_bfloat16*)lds_raw;             // 64 x 264
    __hip_bfloat16* w_lds  = (__hip_bfloat16*)(lds_raw + 33792);   // 64 x 264
    __hip_bfloat16* st_lds = (__hip_bfloat16*)(lds_raw + 67584);   // 128 x 40

    const int bid = blockIdx.x, t = threadIdx.x;

    if (bid >= 576) {                       // ---- norm ----
        int i0 = (bid - 576) * 4, j = t;
        float a0 = 0.f, a1 = 0.f, a2 = 0.f, a3 = 0.f;
        for (int s = 0; s < S_DIM; ++s) {
            float mj = mask[s * N_DIM + j];
            a0 += mask[s * N_DIM + i0 + 0] * mj;
            a1 += mask[s * N_DIM + i0 + 1] * mj;
            a2 += mask[s * N_DIM + i0 + 2] * mj;
            a3 += mask[s * N_DIM + i0 + 3] * mj;
        }
        ninv[(i0 + 0) * N_DIM + j] = 1.0f / (a0 + 1e-3f);
        ninv[(i0 + 1) * N_DIM + j] = 1.0f / (a1 + 1e-3f);
        ninv[(i0 + 2) * N_DIM + j] = 1.0f / (a2 + 1e-3f);
        ninv[(i0 + 3) * N_DIM + j] = 1.0f / (a3 + 1e-3f);
        return;
    }
    if (bid >= 512) {                       // ---- wot ----
        int fidx = (bid - 512) * 256 + t;   // 16384 lane-slots
        int l  = fidx & 63;
        int d  = (fidx >> 6) & 31;
        int zt = fidx >> 11;
        int z  = zt * 16 + (l & 15);
        int cb = (l >> 4) * 8;
        short8 frag;
        #pragma unroll
        for (int j = 0; j < 8; ++j)
            frag[j] = f2bf(wo[(size_t)((cb + j) * 32 + d) * CZ + z]);
        *(short8*)&wo_f[(size_t)fidx * 8] = frag;
        return;
    }

    // ---- prep: 2 n x 32 s per block ----
    const int lane = t & 63, wv = t >> 6;
    const int q = lane >> 4, c16 = lane & 15;
    const int n0 = (bid & 127) * 2, s0 = (bid >> 7) * 32, sk = bid >> 7;

    #pragma unroll 4
    for (int i = 0; i < 64; ++i) {
        int e = i * 256 + t;
        int k = e >> 6, c = e & 63;
        float v = (c < CH) ? w1[k * CH + c] : w2[k * CH + (c - CH)];
        w_lds[c * 264 + k] = __float2bfloat16(v);
    }

    float4 lw = ((const float4*)lnw)[lane];
    float4 lb = ((const float4*)lnb)[lane];

    #pragma unroll 2
    for (int it = 0; it < 16; ++it) {
        int rl = wv * 16 + it;
        int r  = (s0 + (rl >> 1)) * N_DIM + n0 + (rl & 1);
        float4 mv = ((const float4*)(m + (size_t)r * CM))[lane];
        float s1 = mv.x + mv.y + mv.z + mv.w;
        float s2 = mv.x*mv.x + mv.y*mv.y + mv.z*mv.z + mv.w*mv.w;
        #pragma unroll
        for (int o = 32; o > 0; o >>= 1) {
            s1 += __shfl_xor(s1, o, 64);
            s2 += __shfl_xor(s2, o, 64);
        }
        float mu  = s1 * (1.0f / 256.0f);
        float var = s2 * (1.0f / 256.0f) - mu * mu;
        float rs  = rsqrtf(var + 1e-5f);
        int base = rl * 264 + lane * 4;
        ln_lds[base + 0] = __float2bfloat16((mv.x - mu) * rs * lw.x + lb.x);
        ln_lds[base + 1] = __float2bfloat16((mv.y - mu) * rs * lw.y + lb.y);
        ln_lds[base + 2] = __float2bfloat16((mv.z - mu) * rs * lw.z + lb.z);
        ln_lds[base + 3] = __float2bfloat16((mv.w - mu) * rs * lw.w + lb.w);
    }
    __syncthreads();

    float4v acc[4];
    #pragma unroll
    for (int ct = 0; ct < 4; ++ct) acc[ct] = (float4v){0.f, 0.f, 0.f, 0.f};
    #pragma unroll
    for (int ks = 0; ks < 8; ++ks) {
        int k0 = ks * 32 + q * 8;
        short8 af = *(const short8*)&ln_lds[(wv * 16 + c16) * 264 + k0];
        #pragma unroll
        for (int ct = 0; ct < 4; ++ct) {
            short8 wb = *(const short8*)&w_lds[(ct * 16 + c16) * 264 + k0];
            acc[ct] = __builtin_amdgcn_mfma_f32_16x16x32_bf16(af, wb, acc[ct], 0, 0, 0);
        }
    }

    #pragma unroll
    for (int ct = 0; ct < 4; ++ct) {
        int cc = ct * 16 + c16;
        float bias = (cc < CH) ? b1[cc] : b2[cc - CH];
        #pragma unroll
        for (int rr = 0; rr < 4; ++rr) {
            int rl = wv * 16 + q * 4 + rr;
            int r  = (s0 + (rl >> 1)) * N_DIM + n0 + (rl & 1);
            float val = (acc[ct][rr] + bias) * mask[r];
            st_lds[((rl & 1) * 64 + cc) * 40 + (rl >> 1)] = __float2bfloat16(val);
        }
    }
    __syncthreads();

    #pragma unroll
    for (int i = 0; i < 2; ++i) {
        int slot = i * 256 + t;
        int f8 = slot >> 6, l = slot & 63;
        int fl = f8 & 3, nl = fl >> 1, cch = fl & 1;
        int lq = l >> 4, lc16 = l & 15;
        int col = nl * 64 + (f8 >= 4 ? 32 : 0) + cch * 16 + lc16;
        short8 v = *(const short8*)&st_lds[col * 40 + lq * 8];
        __hip_bfloat16* base = (f8 >= 4) ? b_f : a_f;
        *(short8*)&base[(size_t)((n0 * 2 + fl) * 4 + sk) * 512 + l * 8] = v;
    }
}

// ---------------------------------------------------------------------------
// Main kernel v8: 512 thr (8 waves), 128 I x 256 J, R8's combined epilogue
// (wo_f once) + single-burst async staging of BOTH taus' B + 4 barriers.
// LDS: R_A [0,16640): B(t0) then P_t0;  R_B [16640,33280): B(t1) then P_t1.
// Sequence: [DMA both B + af loads][bar][MFMA t0][bar][scatter P0 + MFMA t1]
//           [bar][scatter P1][bar][epilogue, wo_f read once].
// ---------------------------------------------------------------------------
__global__ __launch_bounds__(512, 4) void main_kernel(
    const __hip_bfloat16* __restrict__ a_f, const __hip_bfloat16* __restrict__ b_f,
    const __hip_bfloat16* __restrict__ wo_f, const float* __restrict__ bo,
    const float* __restrict__ ninv, float* __restrict__ out)
{
    __shared__ __align__(16) short lds[33280];

    const int t = threadIdx.x, l = t & 63, wv = t >> 6;   // wv 0..7
    const int q = l >> 4, c16 = l & 15;
    const int bi = blockIdx.x, bj0 = blockIdx.y * 2;
    const int wr = wv & 3, wc = wv >> 2;
    const size_t Ix = (size_t)bi * 8;

    // issue BOTH taus' B stages as direct-to-LDS DMA (async, 0 VGPR)
    #pragma unroll
    for (int tau = 0; tau < 2; ++tau) {
        const size_t Jx = (size_t)(bj0 + tau) * 8;
        #pragma unroll
        for (int i = 0; i < 4; ++i) {
            int f = i * 8 + wv;
            __builtin_amdgcn_global_load_lds(
                (AS1 const void*)&b_f[((Jx + (f >> 2)) * 4 + (f & 3)) * 512 + l * 8],
                (AS3 void*)&lds[tau * 16640 + f * 512], 16, 0, 0);
        }
    }

    // A fragments -> registers (overlaps the DMAs)
    short8 af[4][2];
    #pragma unroll
    for (int sk = 0; sk < 4; ++sk)
        #pragma unroll
        for (int ti = 0; ti < 2; ++ti)
            af[sk][ti] = *(const short8*)&a_f[((Ix + wr * 2 + ti) * 4 + sk) * 512 + l * 8];

    __syncthreads();   // bar1: both B stages visible

    // ---- MFMA tau0 (reads R_A) ----
    float4v accA[2][4];
    #pragma unroll
    for (int ti = 0; ti < 2; ++ti)
        #pragma unroll
        for (int tj = 0; tj < 4; ++tj)
            accA[ti][tj] = (float4v){0.f, 0.f, 0.f, 0.f};
    #pragma unroll
    for (int sk = 0; sk < 4; ++sk) {
        short8 bf[4];
        #pragma unroll
        for (int tj = 0; tj < 4; ++tj)
            bf[tj] = *(const short8*)&lds[((wc * 4 + tj) * 4 + sk) * 512 + l * 8];
        #pragma unroll
        for (int tj = 0; tj < 4; ++tj) {
            accA[0][tj] = __builtin_amdgcn_mfma_f32_16x16x32_bf16(af[sk][0], bf[tj], accA[0][tj], 0, 0, 0);
            accA[1][tj] = __builtin_amdgcn_mfma_f32_16x16x32_bf16(af[sk][1], bf[tj], accA[1][tj], 0, 0, 0);
        }
    }
    __syncthreads();   // bar2: all waves done reading B(t0)

    // ---- scatter P0 over R_A, and MFMA tau1 (reads R_B) ----
    #pragma unroll
    for (int ti = 0; ti < 2; ++ti)
        #pragma unroll
        for (int tj = 0; tj < 4; ++tj) {
            int d  = ((tj & 1) * 16) + c16;
            int c0 = ti * 16 + q * 4;
            int p  = wr * 4 + wc * 2 + (tj >> 1);
            short4v pk;
            #pragma unroll
            for (int rr = 0; rr < 4; ++rr)
                pk[rr] = f2bf(accA[ti][tj][rr]);
            *(short4v*)&lds[d * 520 + (c0 >> 3) * 128 + p * 8 + (c0 & 7)] = pk;
        }

    float4v accB[2][4];
    #pragma unroll
    for (int ti = 0; ti < 2; ++ti)
        #pragma unroll
        for (int tj = 0; tj < 4; ++tj)
            accB[ti][tj] = (float4v){0.f, 0.f, 0.f, 0.f};
    #pragma unroll
    for (int sk = 0; sk < 4; ++sk) {
        short8 bf[4];
        #pragma unroll
        for (int tj = 0; tj < 4; ++tj)
            bf[tj] = *(const short8*)&lds[16640 + ((wc * 4 + tj) * 4 + sk) * 512 + l * 8];
        #pragma unroll
        for (int tj = 0; tj < 4; ++tj) {
            accB[0][tj] = __builtin_amdgcn_mfma_f32_16x16x32_bf16(af[sk][0], bf[tj], accB[0][tj], 0, 0, 0);
            accB[1][tj] = __builtin_amdgcn_mfma_f32_16x16x32_bf16(af[sk][1], bf[tj], accB[1][tj], 0, 0, 0);
        }
    }
    __syncthreads();   // bar3: P0 written everywhere, B(t1) reads done

    // ---- scatter P1 over R_B ----
    #pragma unroll
    for (int ti = 0; ti < 2; ++ti)
        #pragma unroll
        for (int tj = 0; tj < 4; ++tj) {
            int d  = ((tj & 1) * 16) + c16;
            int c0 = ti * 16 + q * 4;
            int p  = wr * 4 + wc * 2 + (tj >> 1);
            short4v pk;
            #pragma unroll
            for (int rr = 0; rr < 4; ++rr)
                pk[rr] = f2bf(accB[ti][tj][rr]);
            *(short4v*)&lds[16640 + d * 520 + (c0 >> 3) * 128 + p * 8 + (c0 & 7)] = pk;
        }
    __syncthreads();   // bar4: both P's ready

    // ---- combined epilogue: wo_f read ONCE; wave wv owns z-tile wv ----
    float4v oacc[2];
    oacc[0] = (float4v){0.f, 0.f, 0.f, 0.f};
    oacc[1] = (float4v){0.f, 0.f, 0.f, 0.f};
    const __hip_bfloat16* wbase = wo_f + (size_t)wv * 32 * 512;
    #pragma unroll 4
    for (int d = 0; d < 32; ++d) {
        short8 p0 = *(const short8*)&lds[        d * 520 + l * 8];
        short8 p1 = *(const short8*)&lds[16640 + d * 520 + l * 8];
        short8 wf = *(const short8*)&wbase[(size_t)(d * 512 + l * 8)];
        oacc[0] = __builtin_amdgcn_mfma_f32_16x16x32_bf16(p0, wf, oacc[0], 0, 0, 0);
        oacc[1] = __builtin_amdgcn_mfma_f32_16x16x32_bf16(p1, wf, oacc[1], 0, 0, 0);
    }

    // D: row = pair = q*4+rr; col = z offset = c16. z = wv*16 + c16.
    const int gi = bi * 4 + q;
    const int z  = wv * 16 + c16;
    const float bz = bo[z];
    #pragma unroll
    for (int tau = 0; tau < 2; ++tau) {
        const int bj = bj0 + tau;
        #pragma unroll
        for (int rr = 0; rr < 4; ++rr) {
            int gj = bj * 4 + rr;
            float nv = ninv[gi * N_DIM + gj];
            out[((size_t)gi * N_DIM + gj) * CZ + z] = (oacc[tau][rr] + bz) * nv;
        }
    }
}

extern "C" void kernel_launch(void* const* d_in, const int* in_sizes, int n_in,
                              void* d_out, int out_size, void* d_ws, size_t ws_size,
                              hipStream_t stream) {
    const float* m    = (const float*)d_in[0];
    const float* mask = (const float*)d_in[1];
    const float* lnw  = (const float*)d_in[2];
    const float* lnb  = (const float*)d_in[3];
    const float* w1   = (const float*)d_in[4];
    const float* b1   = (const float*)d_in[5];
    const float* w2   = (const float*)d_in[6];
    const float* b2   = (const float*)d_in[7];
    const float* wo   = (const float*)d_in[8];
    const float* bo   = (const float*)d_in[9];
    float* out = (float*)d_out;

    char* ws = (char*)d_ws;
    __hip_bfloat16* a_f  = (__hip_bfloat16*)ws;                          // 2 MB
    __hip_bfloat16* b_f  = (__hip_bfloat16*)(ws + (2u << 20));           // 2 MB
    __hip_bfloat16* wo_f = (__hip_bfloat16*)(ws + (4u << 20));           // 256 KB
    float*          ninv = (float*)(ws + (4u << 20) + (256u << 10));     // 256 KB

    prep_aux_kernel<<<640, 256, 0, stream>>>(m, mask, lnw, lnb, w1, b1, w2, b2,
                                             wo, bo, a_f, b_f, wo_f, ninv);
    main_kernel<<<dim3(64, 32), 512, 0, stream>>>(a_f, b_f, wo_f, bo, ninv, out);
}